// Round 3
// baseline (359.508 us; speedup 1.0000x reference)
//
#include <hip/hip_runtime.h>
#include <hip/hip_bf16.h>

typedef __bf16 bf16x8 __attribute__((ext_vector_type(8)));
typedef unsigned short ushort8 __attribute__((ext_vector_type(8)));
typedef unsigned short ushort4v __attribute__((ext_vector_type(4)));
typedef float f32x4 __attribute__((ext_vector_type(4)));

__device__ __forceinline__ unsigned short f2bf(float f) {
    union { float f; unsigned int i; } v;
    v.f = f;
    unsigned int i = v.i;
    i += 0x7fffu + ((i >> 16) & 1u);  // round-to-nearest-even
    return (unsigned short)(i >> 16);
}

union bfcast { ushort8 u; bf16x8 b; };

__device__ __forceinline__ bf16x8 load_w8_f32(const float* p) {
    const float4 f0 = *(const float4*)p;
    const float4 f1 = *(const float4*)(p + 4);
    bfcast c;
    c.u[0] = f2bf(f0.x); c.u[1] = f2bf(f0.y); c.u[2] = f2bf(f0.z); c.u[3] = f2bf(f0.w);
    c.u[4] = f2bf(f1.x); c.u[5] = f2bf(f1.y); c.u[6] = f2bf(f1.z); c.u[7] = f2bf(f1.w);
    return c.b;
}

__device__ __forceinline__ float fast_tanh(float x) {
    float e = __expf(2.0f * x);
    return 1.0f - 2.0f * __builtin_amdgcn_rcpf(e + 1.0f);
}

// Fused prep: blocks 0-24 enc proj, 25-31 dec proj, 32-281 convert W_out->bf16.
// Proj: C = A(Ma x 512, f32) @ W^T(512x512 f32, inline bf16-rounded) + b -> f32.
__global__ __launch_bounds__(256, 2) void prep_kernel(
    const float* __restrict__ enc_in, const float* __restrict__ dec_in,
    const float* __restrict__ W_enc,  const float* __restrict__ b_enc,
    const float* __restrict__ W_dec,  const float* __restrict__ b_dec,
    const float* __restrict__ W_out,
    float* __restrict__ enc_proj, float* __restrict__ dec_proj,
    unsigned short* __restrict__ wout_bf)
{
    const int blk = blockIdx.x;
    const int tid = threadIdx.x;

    if (blk >= 32) {  // ---- convert W_out (256000 f32) to bf16 ----
        const int i = (blk - 32) * 1024 + tid * 4;
        const float4 v = *(const float4*)(W_out + i);
        ushort4v p;
        p.x = f2bf(v.x); p.y = f2bf(v.y); p.z = f2bf(v.z); p.w = f2bf(v.w);
        *(ushort4v*)(wout_bf + i) = p;
        return;
    }

    // ---- projection ----
    const float *A, *W, *bias; float* outp; int Ma, r0;
    if (blk < 25) { A = enc_in; W = W_enc; bias = b_enc; outp = enc_proj; Ma = 1600; r0 = blk * 64; }
    else          { A = dec_in; W = W_dec; bias = b_dec; outp = dec_proj; Ma = 400;  r0 = (blk - 25) * 64; }

    __shared__ unsigned short tile[64 * 520];
    {   // stage A tile fp32 -> bf16: 4 threads per row
        const int row = tid >> 2, q = tid & 3;
        int gr = r0 + row;
        if (gr >= Ma) gr = Ma - 1;
        const float* src = A + (size_t)gr * 512;
        ushort8* dst = (ushort8*)(tile + row * 520);
        #pragma unroll
        for (int i = 0; i < 16; ++i) {
            const int c = q + i * 4;
            const int k = c * 8;
            const float4 a0 = *(const float4*)(src + k);
            const float4 a1 = *(const float4*)(src + k + 4);
            bfcast pk;
            pk.u[0] = f2bf(a0.x); pk.u[1] = f2bf(a0.y); pk.u[2] = f2bf(a0.z); pk.u[3] = f2bf(a0.w);
            pk.u[4] = f2bf(a1.x); pk.u[5] = f2bf(a1.y); pk.u[6] = f2bf(a1.z); pk.u[7] = f2bf(a1.w);
            dst[c] = pk.u;
        }
    }
    __syncthreads();

    const int wave = tid >> 6, lane = tid & 63;
    const int lrow = lane & 15;
    const int lk8  = (lane >> 4) * 8;
    const int j0   = wave * 128;

    f32x4 acc[4][8];
    #pragma unroll
    for (int mi = 0; mi < 4; ++mi)
        #pragma unroll
        for (int ji = 0; ji < 8; ++ji)
            acc[mi][ji] = (f32x4){0.f, 0.f, 0.f, 0.f};

    const float* wbase = W + (size_t)(j0 + lrow) * 512 + lk8;
    const unsigned short* abase = tile + lrow * 520 + lk8;

    for (int kk = 0; kk < 512; kk += 32) {
        bf16x8 a[4], b[8];
        #pragma unroll
        for (int mi = 0; mi < 4; ++mi)
            a[mi] = *(const bf16x8*)(abase + mi * 16 * 520 + kk);
        #pragma unroll
        for (int ji = 0; ji < 8; ++ji)
            b[ji] = load_w8_f32(wbase + (size_t)ji * 16 * 512 + kk);
        #pragma unroll
        for (int mi = 0; mi < 4; ++mi)
            #pragma unroll
            for (int ji = 0; ji < 8; ++ji)
                acc[mi][ji] = __builtin_amdgcn_mfma_f32_16x16x32_bf16(
                    a[mi], b[ji], acc[mi][ji], 0, 0, 0);
    }

    const int crow = (lane >> 4) * 4;
    const int ccol = lane & 15;
    #pragma unroll
    for (int ji = 0; ji < 8; ++ji) {
        const int col = j0 + ji * 16 + ccol;
        const float bv = bias[col];
        #pragma unroll
        for (int mi = 0; mi < 4; ++mi)
            #pragma unroll
            for (int rg = 0; rg < 4; ++rg) {
                const int gr = r0 + mi * 16 + crow + rg;
                if (gr < Ma) outp[(size_t)gr * 512 + col] = acc[mi][ji][rg] + bv;
            }
    }
}

// out[r, v] = sum_k tanh(enc[n,t,k] + dec[n,u,k]) * Wout[v,k] + bout[v]
// 512 thr = 8 waves; 64 rows/block; wave w owns v in [w*64, w*64+64). 1250 blocks.
__global__ __launch_bounds__(512, 4) void joiner_kernel(
    const float* __restrict__ encp,          // 1600 x 512 f32 (ws)
    const float* __restrict__ decp,          // 400 x 512 f32 (ws)
    const unsigned short* __restrict__ Wout, // 500 x 512 bf16 (ws)
    const float* __restrict__ bout,          // 500 f32
    float* __restrict__ out)                 // 80000 x 500 f32
{
    __shared__ unsigned short tile[64 * 520];
    const int tid = threadIdx.x;
    const int r0 = blockIdx.x * 64;

    {   // phase 1: x-tile = tanh(enc+dec) -> bf16, 8 threads per row
        const int row = tid >> 3, q = tid & 7;
        const int r = r0 + row;
        const int n = r / 10000;
        const int rem = r % 10000;
        const int t = rem / 50;
        const int u = rem - t * 50;
        const float* erow = encp + (size_t)(n * 200 + t) * 512;
        const float* drow = decp + (size_t)(n * 50 + u) * 512;
        ushort8* dst = (ushort8*)(tile + row * 520);
        #pragma unroll
        for (int i = 0; i < 8; ++i) {
            const int c = q + i * 8;
            const int k = c * 8;
            const float4 ev0 = *(const float4*)(erow + k);
            const float4 ev1 = *(const float4*)(erow + k + 4);
            const float4 dv0 = *(const float4*)(drow + k);
            const float4 dv1 = *(const float4*)(drow + k + 4);
            float xs[8] = {ev0.x + dv0.x, ev0.y + dv0.y, ev0.z + dv0.z, ev0.w + dv0.w,
                           ev1.x + dv1.x, ev1.y + dv1.y, ev1.z + dv1.z, ev1.w + dv1.w};
            bfcast pk;
            #pragma unroll
            for (int j = 0; j < 8; ++j) pk.u[j] = f2bf(fast_tanh(xs[j]));
            dst[c] = pk.u;
        }
    }
    __syncthreads();

    // phase 2: barrier-free K-loop. 8 waves x 64 v-cols.
    const int wave = tid >> 6, lane = tid & 63;
    const int lrow = lane & 15;
    const int lk8  = (lane >> 4) * 8;
    const int v0   = wave * 64;

    f32x4 acc[4][4];
    #pragma unroll
    for (int mi = 0; mi < 4; ++mi)
        #pragma unroll
        for (int ji = 0; ji < 4; ++ji)
            acc[mi][ji] = (f32x4){0.f, 0.f, 0.f, 0.f};

    const unsigned short* wrow[4];
    #pragma unroll
    for (int ji = 0; ji < 4; ++ji) {
        int v = v0 + ji * 16 + lrow;
        if (v > 499) v = 499;  // cols >=500 computed but never stored
        wrow[ji] = Wout + (size_t)v * 512 + lk8;
    }
    const unsigned short* abase = tile + lrow * 520 + lk8;

    for (int kk = 0; kk < 512; kk += 32) {
        bf16x8 a[4], b[4];
        #pragma unroll
        for (int mi = 0; mi < 4; ++mi)
            a[mi] = *(const bf16x8*)(abase + mi * 16 * 520 + kk);
        #pragma unroll
        for (int ji = 0; ji < 4; ++ji)
            b[ji] = *(const bf16x8*)(wrow[ji] + kk);
        #pragma unroll
        for (int mi = 0; mi < 4; ++mi)
            #pragma unroll
            for (int ji = 0; ji < 4; ++ji)
                acc[mi][ji] = __builtin_amdgcn_mfma_f32_16x16x32_bf16(
                    a[mi], b[ji], acc[mi][ji], 0, 0, 0);
    }

    const int crow = (lane >> 4) * 4;
    const int ccol = lane & 15;
    #pragma unroll
    for (int ji = 0; ji < 4; ++ji) {
        const int v = v0 + ji * 16 + ccol;
        if (v < 500) {
            const float bv = bout[v];
            #pragma unroll
            for (int mi = 0; mi < 4; ++mi)
                #pragma unroll
                for (int rg = 0; rg < 4; ++rg) {
                    const size_t gr = (size_t)(r0 + mi * 16 + crow + rg);
                    // non-temporal: keep 160MB output stream from evicting L2
                    __builtin_nontemporal_store(acc[mi][ji][rg] + bv,
                                                out + gr * 500 + v);
                }
        }
    }
}

extern "C" void kernel_launch(void* const* d_in, const int* in_sizes, int n_in,
                              void* d_out, int out_size, void* d_ws, size_t ws_size,
                              hipStream_t stream) {
    (void)in_sizes; (void)n_in; (void)out_size; (void)ws_size;
    const float* enc_in = (const float*)d_in[0]; // 8x200x512 f32
    const float* dec_in = (const float*)d_in[1]; // 8x50x512 f32
    const float* W_enc  = (const float*)d_in[2]; // 512x512 f32
    const float* b_enc  = (const float*)d_in[3]; // 512 f32
    const float* W_dec  = (const float*)d_in[4]; // 512x512 f32
    const float* b_dec  = (const float*)d_in[5]; // 512 f32
    const float* W_out  = (const float*)d_in[6]; // 500x512 f32
    const float* b_out  = (const float*)d_in[7]; // 500 f32
    float* out = (float*)d_out;                  // 8x200x50x500 f32

    float* ws = (float*)d_ws;
    float* enc_proj = ws;                                      // 1600*512 f32
    float* dec_proj = ws + 819200;                             // 400*512 f32
    unsigned short* wout_bf = (unsigned short*)(ws + 1024000); // 256000 bf16

    hipLaunchKernelGGL(prep_kernel, dim3(282), dim3(256), 0, stream,
                       enc_in, dec_in, W_enc, b_enc, W_dec, b_dec, W_out,
                       enc_proj, dec_proj, wout_bf);
    hipLaunchKernelGGL(joiner_kernel, dim3(1250), dim3(512), 0, stream,
                       enc_proj, dec_proj, wout_bf, b_out, out);
}

// Round 4
// 262.158 us; speedup vs baseline: 1.3713x; 1.3713x over previous
//
#include <hip/hip_runtime.h>
#include <hip/hip_bf16.h>

typedef __bf16 bf16x8 __attribute__((ext_vector_type(8)));
typedef unsigned short ushort8 __attribute__((ext_vector_type(8)));
typedef unsigned short ushort4v __attribute__((ext_vector_type(4)));
typedef float f32x4 __attribute__((ext_vector_type(4)));

__device__ __forceinline__ unsigned short f2bf(float f) {
    union { float f; unsigned int i; } v;
    v.f = f;
    unsigned int i = v.i;
    i += 0x7fffu + ((i >> 16) & 1u);  // round-to-nearest-even
    return (unsigned short)(i >> 16);
}

union bfcast { ushort8 u; bf16x8 b; };

__device__ __forceinline__ bf16x8 load_w8_f32(const float* p) {
    const float4 f0 = *(const float4*)p;
    const float4 f1 = *(const float4*)(p + 4);
    bfcast c;
    c.u[0] = f2bf(f0.x); c.u[1] = f2bf(f0.y); c.u[2] = f2bf(f0.z); c.u[3] = f2bf(f0.w);
    c.u[4] = f2bf(f1.x); c.u[5] = f2bf(f1.y); c.u[6] = f2bf(f1.z); c.u[7] = f2bf(f1.w);
    return c.b;
}

__device__ __forceinline__ float fast_tanh(float x) {
    float e = __expf(2.0f * x);
    return 1.0f - 2.0f * __builtin_amdgcn_rcpf(e + 1.0f);
}

// blocks 0..199: enc proj (50 row-tiles x 4 j-quads); 200..251: dec proj (13x4);
// 252..507: W_out fp32 -> bf16, zero-padded to [512][512].
__global__ __launch_bounds__(256, 2) void prep_kernel(
    const float* __restrict__ enc_in, const float* __restrict__ dec_in,
    const float* __restrict__ W_enc,  const float* __restrict__ b_enc,
    const float* __restrict__ W_dec,  const float* __restrict__ b_dec,
    const float* __restrict__ W_out,
    float* __restrict__ enc_proj, float* __restrict__ dec_proj,
    unsigned short* __restrict__ wout_bf)
{
    const int blk = blockIdx.x;
    const int tid = threadIdx.x;

    if (blk >= 252) {  // ---- W_out convert + zero-pad to 512 rows ----
        const int e = (blk - 252) * 1024 + tid * 4;
        ushort4v p;
        if (e < 256000) {  // 500*512 real elements
            const float4 v = *(const float4*)(W_out + e);
            p.x = f2bf(v.x); p.y = f2bf(v.y); p.z = f2bf(v.z); p.w = f2bf(v.w);
        } else {
            p.x = 0; p.y = 0; p.z = 0; p.w = 0;
        }
        *(ushort4v*)(wout_bf + e) = p;
        return;
    }

    // ---- projection: 32 rows x 128 cols per block ----
    const float *A, *W, *bias; float* outp; int Ma, t, jq;
    if (blk < 200) { A = enc_in; W = W_enc; bias = b_enc; outp = enc_proj;
                     Ma = 1600; t = blk >> 2; jq = blk & 3; }
    else           { const int b2 = blk - 200;
                     A = dec_in; W = W_dec; bias = b_dec; outp = dec_proj;
                     Ma = 400;  t = b2 >> 2;  jq = b2 & 3; }
    const int r0 = t * 32;

    __shared__ unsigned short tile[32 * 520];
    {   // stage A fp32->bf16: 8 threads per row
        const int row = tid >> 3, q = tid & 7;
        int gr = r0 + row;
        if (gr >= Ma) gr = Ma - 1;
        const float* src = A + (size_t)gr * 512;
        ushort8* dst = (ushort8*)(tile + row * 520);
        #pragma unroll
        for (int i = 0; i < 8; ++i) {
            const int c = q + i * 8;
            const int k = c * 8;
            const float4 a0 = *(const float4*)(src + k);
            const float4 a1 = *(const float4*)(src + k + 4);
            bfcast pk;
            pk.u[0] = f2bf(a0.x); pk.u[1] = f2bf(a0.y); pk.u[2] = f2bf(a0.z); pk.u[3] = f2bf(a0.w);
            pk.u[4] = f2bf(a1.x); pk.u[5] = f2bf(a1.y); pk.u[6] = f2bf(a1.z); pk.u[7] = f2bf(a1.w);
            dst[c] = pk.u;
        }
    }
    __syncthreads();

    const int wave = tid >> 6, lane = tid & 63;
    const int lrow = lane & 15;
    const int lk8  = (lane >> 4) * 8;
    const int j0   = jq * 128 + wave * 32;

    f32x4 acc[2][2];
    #pragma unroll
    for (int mi = 0; mi < 2; ++mi)
        #pragma unroll
        for (int ji = 0; ji < 2; ++ji)
            acc[mi][ji] = (f32x4){0.f, 0.f, 0.f, 0.f};

    const unsigned short* abase = tile + lrow * 520 + lk8;
    const float* wb0 = W + (size_t)(j0 + lrow) * 512 + lk8;
    const float* wb1 = wb0 + 16 * 512;

    #pragma unroll
    for (int kk = 0; kk < 512; kk += 32) {
        const bf16x8 a0 = *(const bf16x8*)(abase + kk);
        const bf16x8 a1 = *(const bf16x8*)(abase + 16 * 520 + kk);
        const bf16x8 b0 = load_w8_f32(wb0 + kk);
        const bf16x8 b1 = load_w8_f32(wb1 + kk);
        acc[0][0] = __builtin_amdgcn_mfma_f32_16x16x32_bf16(a0, b0, acc[0][0], 0, 0, 0);
        acc[0][1] = __builtin_amdgcn_mfma_f32_16x16x32_bf16(a0, b1, acc[0][1], 0, 0, 0);
        acc[1][0] = __builtin_amdgcn_mfma_f32_16x16x32_bf16(a1, b0, acc[1][0], 0, 0, 0);
        acc[1][1] = __builtin_amdgcn_mfma_f32_16x16x32_bf16(a1, b1, acc[1][1], 0, 0, 0);
    }

    const int crow = (lane >> 4) * 4;
    const int ccol = lane & 15;
    #pragma unroll
    for (int ji = 0; ji < 2; ++ji) {
        const int col = j0 + ji * 16 + ccol;
        const float bv = bias[col];
        #pragma unroll
        for (int mi = 0; mi < 2; ++mi)
            #pragma unroll
            for (int rg = 0; rg < 4; ++rg) {
                const int gr = r0 + mi * 16 + crow + rg;
                if (gr < Ma) outp[(size_t)gr * 512 + col] = acc[mi][ji][rg] + bv;
            }
    }
}

// out[r, v] = sum_k tanh(enc[n,t,k] + dec[n,u,k]) * Wout[v,k] + bout[v]
// 512 thr = 8 waves; 64 rows/block; wave w owns v in [w*64, w*64+64). 1250 blocks.
// K-loop: fully unrolled, depth-2 register prefetch of B.
// Epilogue: LDS transpose (two 32-row halves) -> contiguous float4 stores.
__global__ __launch_bounds__(512, 4) void joiner_kernel(
    const float* __restrict__ encp,          // 1600 x 512 f32 (ws)
    const float* __restrict__ decp,          // 400 x 512 f32 (ws)
    const unsigned short* __restrict__ Wout, // 512 x 512 bf16, rows >=500 zero (ws)
    const float* __restrict__ bout,          // 500 f32
    float* __restrict__ out)                 // 80000 x 500 f32
{
    __shared__ float4 smem[4160];            // 66560 B: ushort[64*520] | float[32*516]
    unsigned short* tile = (unsigned short*)smem;
    const int tid = threadIdx.x;
    const int r0 = blockIdx.x * 64;

    {   // phase 1: x-tile = tanh(enc+dec) -> bf16, 8 threads per row
        const int row = tid >> 3, q = tid & 7;
        const int r = r0 + row;
        const int n = r / 10000;
        const int rem = r % 10000;
        const int t = rem / 50;
        const int u = rem - t * 50;
        const float* erow = encp + (size_t)(n * 200 + t) * 512;
        const float* drow = decp + (size_t)(n * 50 + u) * 512;
        ushort8* dst = (ushort8*)(tile + row * 520);
        #pragma unroll
        for (int i = 0; i < 8; ++i) {
            const int c = q + i * 8;
            const int k = c * 8;
            const float4 ev0 = *(const float4*)(erow + k);
            const float4 ev1 = *(const float4*)(erow + k + 4);
            const float4 dv0 = *(const float4*)(drow + k);
            const float4 dv1 = *(const float4*)(drow + k + 4);
            float xs[8] = {ev0.x + dv0.x, ev0.y + dv0.y, ev0.z + dv0.z, ev0.w + dv0.w,
                           ev1.x + dv1.x, ev1.y + dv1.y, ev1.z + dv1.z, ev1.w + dv1.w};
            bfcast pk;
            #pragma unroll
            for (int j = 0; j < 8; ++j) pk.u[j] = f2bf(fast_tanh(xs[j]));
            dst[c] = pk.u;
        }
    }
    __syncthreads();

    const int wave = tid >> 6, lane = tid & 63;
    const int lrow = lane & 15;
    const int lk8  = (lane >> 4) * 8;
    const int v0   = wave * 64;

    f32x4 acc[4][4];
    #pragma unroll
    for (int mi = 0; mi < 4; ++mi)
        #pragma unroll
        for (int ji = 0; ji < 4; ++ji)
            acc[mi][ji] = (f32x4){0.f, 0.f, 0.f, 0.f};

    const unsigned short* wrow[4];
    #pragma unroll
    for (int ji = 0; ji < 4; ++ji)
        wrow[ji] = Wout + (size_t)(v0 + ji * 16 + lrow) * 512 + lk8;
    const unsigned short* abase = tile + lrow * 520 + lk8;

    // depth-2 software pipeline on B (global, L2-resident)
    bf16x8 breg[2][4];
    #pragma unroll
    for (int ji = 0; ji < 4; ++ji) breg[0][ji] = *(const bf16x8*)(wrow[ji]);
    #pragma unroll
    for (int ji = 0; ji < 4; ++ji) breg[1][ji] = *(const bf16x8*)(wrow[ji] + 32);

    #pragma unroll
    for (int kk = 0; kk < 16; ++kk) {
        bf16x8 a[4];
        #pragma unroll
        for (int mi = 0; mi < 4; ++mi)
            a[mi] = *(const bf16x8*)(abase + mi * 16 * 520 + kk * 32);
        bf16x8 bn[4];
        if (kk < 14) {
            #pragma unroll
            for (int ji = 0; ji < 4; ++ji)
                bn[ji] = *(const bf16x8*)(wrow[ji] + (kk + 2) * 32);
        }
        #pragma unroll
        for (int mi = 0; mi < 4; ++mi)
            #pragma unroll
            for (int ji = 0; ji < 4; ++ji)
                acc[mi][ji] = __builtin_amdgcn_mfma_f32_16x16x32_bf16(
                    a[mi], breg[kk & 1][ji], acc[mi][ji], 0, 0, 0);
        if (kk < 14) {
            #pragma unroll
            for (int ji = 0; ji < 4; ++ji) breg[kk & 1][ji] = bn[ji];
        }
    }

    // epilogue: two half-tiles through LDS, then contiguous float4 row stores
    float* ob = (float*)smem;                // 32 rows x stride 516 f32
    const int crow = (lane >> 4) * 4;
    const int ccol = lane & 15;
    const int srow = tid >> 4, sslot = tid & 15;   // 32 rows x 16 slots
    #pragma unroll
    for (int h = 0; h < 2; ++h) {
        __syncthreads();   // h=0: all K-loop tile reads done; h=1: prev stores done
        #pragma unroll
        for (int mi2 = 0; mi2 < 2; ++mi2) {
            const int mi = h * 2 + mi2;
            #pragma unroll
            for (int ji = 0; ji < 4; ++ji) {
                const int v = v0 + ji * 16 + ccol;
                const float bv = (v < 500) ? bout[v] : 0.f;
                #pragma unroll
                for (int rg = 0; rg < 4; ++rg)
                    ob[(mi2 * 16 + crow + rg) * 516 + v] = acc[mi][ji][rg] + bv;
            }
        }
        __syncthreads();
        const size_t gr = (size_t)(r0 + h * 32 + srow);
        const float* src = ob + srow * 516;
        float* drow = out + gr * 500;
        #pragma unroll
        for (int i = 0; i < 8; ++i) {
            const int c = sslot + 16 * i;
            if (c < 125)
                *(float4*)(drow + c * 4) = *(const float4*)(src + c * 4);
        }
    }
}

extern "C" void kernel_launch(void* const* d_in, const int* in_sizes, int n_in,
                              void* d_out, int out_size, void* d_ws, size_t ws_size,
                              hipStream_t stream) {
    (void)in_sizes; (void)n_in; (void)out_size; (void)ws_size;
    const float* enc_in = (const float*)d_in[0]; // 8x200x512 f32
    const float* dec_in = (const float*)d_in[1]; // 8x50x512 f32
    const float* W_enc  = (const float*)d_in[2]; // 512x512 f32
    const float* b_enc  = (const float*)d_in[3]; // 512 f32
    const float* W_dec  = (const float*)d_in[4]; // 512x512 f32
    const float* b_dec  = (const float*)d_in[5]; // 512 f32
    const float* W_out  = (const float*)d_in[6]; // 500x512 f32
    const float* b_out  = (const float*)d_in[7]; // 500 f32
    float* out = (float*)d_out;                  // 8x200x50x500 f32

    float* ws = (float*)d_ws;
    float* enc_proj = ws;                                      // 1600*512 f32
    float* dec_proj = ws + 819200;                             // 400*512 f32
    unsigned short* wout_bf = (unsigned short*)(ws + 1024000); // 512*512 bf16 (padded)

    hipLaunchKernelGGL(prep_kernel, dim3(508), dim3(256), 0, stream,
                       enc_in, dec_in, W_enc, b_enc, W_dec, b_dec, W_out,
                       enc_proj, dec_proj, wout_bf);
    hipLaunchKernelGGL(joiner_kernel, dim3(1250), dim3(512), 0, stream,
                       enc_proj, dec_proj, wout_bf, b_out, out);
}